// Round 1
// baseline (1664.240 us; speedup 1.0000x reference)
//
#include <hip/hip_runtime.h>
#include <hip/hip_fp16.h>

typedef _Float16 half_t;
typedef __attribute__((ext_vector_type(8))) _Float16 half8;
typedef __attribute__((ext_vector_type(4))) float f32x4;

#define AS1 __attribute__((address_space(1)))
#define AS3 __attribute__((address_space(3)))

__device__ __forceinline__ void gload16(const half_t* g, half_t* l) {
  __builtin_amdgcn_global_load_lds((const AS1 void*)g, (AS3 void*)l, 16, 0, 0);
}

// ---------------- B-spline basis (grid_size=5, order=3 -> 8 coefs, 12 knots)
__device__ __forceinline__ void bspline8(float x, const float g[12], float out[8]) {
  float b[11];
#pragma unroll
  for (int j = 0; j < 11; ++j)
    b[j] = (x >= g[j] && x < g[j + 1]) ? 1.0f : 0.0f;
#pragma unroll
  for (int k = 1; k <= 3; ++k) {
#pragma unroll
    for (int j = 0; j + k < 11; ++j) {
      float ln = x - g[j];
      float ld = g[j + k] - g[j];
      float rn = g[j + k + 1] - x;
      float rd = g[j + k + 1] - g[j + 1];
      b[j] = (ln / ld) * b[j] + (rn / rd) * b[j + 1];
    }
  }
#pragma unroll
  for (int j = 0; j < 8; ++j) out[j] = b[j];
}

// ---------------- weight conversion: fp32 (base,spline*scaler) -> fp16, layout
// W[chunk][o][ 0..1023 base | 1024 + il*8 + k spline ]
__global__ void wconv_kernel(const float* __restrict__ bw, const float* __restrict__ sw,
                             const float* __restrict__ sc, half_t* __restrict__ W,
                             int O, int ibits) {
  int idx = blockIdx.x * 256 + threadIdx.x;
  int o = idx >> ibits;
  int i = idx & ((1 << ibits) - 1);
  int c = i >> 10;
  int il = i & 1023;
  float b = bw[idx];
  float scv = sc[idx];
  const float4* svp = (const float4*)sw;
  float4 s0 = svp[(size_t)idx * 2];
  float4 s1 = svp[(size_t)idx * 2 + 1];
  half_t* wrow = W + ((size_t)c * O + o) * 9216;
  wrow[il] = (half_t)b;
  half8 hv;
  hv[0] = (half_t)(s0.x * scv); hv[1] = (half_t)(s0.y * scv);
  hv[2] = (half_t)(s0.z * scv); hv[3] = (half_t)(s0.w * scv);
  hv[4] = (half_t)(s1.x * scv); hv[5] = (half_t)(s1.y * scv);
  hv[6] = (half_t)(s1.z * scv); hv[7] = (half_t)(s1.w * scv);
  *(half8*)&wrow[1024 + il * 8] = hv;
}

// ---------------- activation expansion: v -> [silu(v) | basis(v)[8]] fp16
template <typename ST>
__global__ void expand_kernel(const ST* __restrict__ src, half_t* __restrict__ dst,
                              int Isrc, int i0, const float* __restrict__ gridp) {
  int idx = blockIdx.x * 256 + threadIdx.x;
  int n = idx >> 10;
  int il = idx & 1023;
  int i = i0 + il;
  float v = (float)src[(size_t)n * Isrc + i];
  const float4* gr = (const float4*)(gridp + (size_t)i * 12);
  float4 ga = gr[0], gb = gr[1], gc = gr[2];
  float g[12] = {ga.x, ga.y, ga.z, ga.w, gb.x, gb.y, gb.z, gb.w, gc.x, gc.y, gc.z, gc.w};
  float bs[8];
  bspline8(v, g, bs);
  half_t* drow = dst + (size_t)n * 9216;
  drow[il] = (half_t)(v / (1.0f + expf(-v)));
  half8 hb;
#pragma unroll
  for (int k = 0; k < 8; ++k) hb[k] = (half_t)bs[k];
  *(half8*)&drow[1024 + il * 8] = hb;
}

// ---------------- GEMM: C(MxN) = A(MxK) * B(NxK)^T, fp16 in, fp32 acc
// MODE 0: gelu(erf) -> Hout fp16 ; 1: Cout = v ; 2: Cout += v ; 3: Cout += v + Res
template <int MODE, int MT, int NT, int WM, int WN>
__global__ __launch_bounds__(256) void gemm_kernel(const half_t* __restrict__ A,
                                                   const half_t* __restrict__ B, int K,
                                                   float* __restrict__ Cout,
                                                   half_t* __restrict__ Hout, int ldc,
                                                   const float* __restrict__ Res) {
  constexpr int BM = WM * MT * 16;
  constexpr int BN = WN * NT * 16;
  constexpr int RA = BM / 16;   // 1KB staging regions in A tile
  constexpr int RB = BN / 16;
  constexpr int LA = RA / 4;    // regions per wave
  constexpr int LB = RB / 4;
  __shared__ __align__(16) half_t As[BM * 32];
  __shared__ __align__(16) half_t Bs[BN * 32];

  const int tid = threadIdx.x;
  const int wid = tid >> 6;
  const int lane = tid & 63;
  const int wm = wid % WM;
  const int wn = wid / WM;
  const int bm = blockIdx.x;
  const int bn = blockIdx.y;

  const half_t* Ab = A + (size_t)bm * BM * K;
  const half_t* Bb = B + (size_t)bn * BN * K;

  const int lrow = lane >> 2;          // row within region
  const int lcol = (lane & 3) * 8;     // col (halves) within row

  const half_t* pa[LA]; half_t* la[LA];
#pragma unroll
  for (int q = 0; q < LA; ++q) {
    int r = wid + q * 4;
    pa[q] = Ab + (size_t)(r * 16 + lrow) * K + lcol;
    la[q] = &As[r * 512];
  }
  const half_t* pb[LB]; half_t* lb[LB];
#pragma unroll
  for (int q = 0; q < LB; ++q) {
    int r = wid + q * 4;
    pb[q] = Bb + (size_t)(r * 16 + lrow) * K + lcol;
    lb[q] = &Bs[r * 512];
  }

  f32x4 acc[MT][NT] = {};
  const int lr = lane & 15;
  const int kb = (lane >> 4) * 8;

  for (int k0 = 0; k0 < K; k0 += 32) {
    __syncthreads();
#pragma unroll
    for (int q = 0; q < LA; ++q) gload16(pa[q] + k0, la[q]);
#pragma unroll
    for (int q = 0; q < LB; ++q) gload16(pb[q] + k0, lb[q]);
    __syncthreads();
    half8 af[MT], bf[NT];
#pragma unroll
    for (int mt = 0; mt < MT; ++mt)
      af[mt] = *(const half8*)&As[(wm * MT * 16 + mt * 16 + lr) * 32 + kb];
#pragma unroll
    for (int nt = 0; nt < NT; ++nt)
      bf[nt] = *(const half8*)&Bs[(wn * NT * 16 + nt * 16 + lr) * 32 + kb];
#pragma unroll
    for (int mt = 0; mt < MT; ++mt)
#pragma unroll
      for (int nt = 0; nt < NT; ++nt)
        acc[mt][nt] = __builtin_amdgcn_mfma_f32_16x16x32_f16(af[mt], bf[nt], acc[mt][nt], 0, 0, 0);
  }

#pragma unroll
  for (int mt = 0; mt < MT; ++mt)
#pragma unroll
    for (int nt = 0; nt < NT; ++nt) {
      int row0 = bm * BM + wm * MT * 16 + mt * 16 + ((lane >> 4) << 2);
      int col = bn * BN + wn * NT * 16 + nt * 16 + lr;
#pragma unroll
      for (int j = 0; j < 4; ++j) {
        float v = acc[mt][nt][j];
        size_t off = (size_t)(row0 + j) * ldc + col;
        if constexpr (MODE == 0) {
          v = 0.5f * v * (1.0f + erff(v * 0.70710678118654752f));
          Hout[off] = (half_t)v;
        } else if constexpr (MODE == 1) {
          Cout[off] = v;
        } else if constexpr (MODE == 2) {
          Cout[off] = Cout[off] + v;
        } else {
          Cout[off] = Cout[off] + v + Res[off];
        }
      }
    }
}

extern "C" void kernel_launch(void* const* d_in, const int* in_sizes, int n_in,
                              void* d_out, int out_size, void* d_ws, size_t ws_size,
                              hipStream_t stream) {
  const float* x   = (const float*)d_in[0];
  const float* bw1 = (const float*)d_in[1];
  const float* sw1 = (const float*)d_in[2];
  const float* sc1 = (const float*)d_in[3];
  const float* bw2 = (const float*)d_in[4];
  const float* sw2 = (const float*)d_in[5];
  const float* sc2 = (const float*)d_in[6];
  const float* g1  = (const float*)d_in[7];
  const float* g2  = (const float*)d_in[8];
  float* out = (float*)d_out;

  // workspace: Wbuf (72MB, reused layer1->layer2), Abuf (72MB), Hh fp16 (32MB)
  half_t* Wbuf = (half_t*)d_ws;
  half_t* Abuf = Wbuf + (size_t)4096 * 9216;
  half_t* Hh   = Abuf + (size_t)4096 * 9216;

  const int T = 256;
  const int NB = (4096 * 1024) / T;  // 16384 blocks for elementwise kernels

  // ---- layer 1 ----
  wconv_kernel<<<NB, T, 0, stream>>>(bw1, sw1, sc1, Wbuf, 4096, 10);
  expand_kernel<float><<<NB, T, 0, stream>>>(x, Abuf, 1024, 0, g1);
  gemm_kernel<0, 4, 4, 2, 2><<<dim3(32, 32), T, 0, stream>>>(Abuf, Wbuf, 9216, nullptr, Hh, 4096, nullptr);

  // ---- layer 2 (K chunked 4 x 9216), W2 overwrites W1 region ----
  wconv_kernel<<<NB, T, 0, stream>>>(bw2, sw2, sc2, Wbuf, 1024, 12);
  for (int c = 0; c < 4; ++c) {
    expand_kernel<half_t><<<NB, T, 0, stream>>>(Hh, Abuf, 4096, c * 1024, g2);
    const half_t* Wc = Wbuf + (size_t)c * 1024 * 9216;
    if (c == 0)
      gemm_kernel<1, 2, 4, 4, 1><<<dim3(32, 16), T, 0, stream>>>(Abuf, Wc, 9216, out, nullptr, 1024, nullptr);
    else if (c < 3)
      gemm_kernel<2, 2, 4, 4, 1><<<dim3(32, 16), T, 0, stream>>>(Abuf, Wc, 9216, out, nullptr, 1024, nullptr);
    else
      gemm_kernel<3, 2, 4, 4, 1><<<dim3(32, 16), T, 0, stream>>>(Abuf, Wc, 9216, out, nullptr, 1024, x);
  }
}